// Round 24
// baseline (2174.365 us; speedup 1.0000x reference)
//
#include <hip/hip_runtime.h>

#define NB 256      // batch
#define TT 1000     // total timesteps
#define HD 128      // hidden
#define NG 512      // 4*H, PyTorch gate order i,f,g,o

// 8 waves/block at 1 block/CU = exactly 2 waves/EU (256-VGPR budget).
#define WGA __attribute__((amdgpu_flat_work_group_size(512,512), amdgpu_waves_per_eu(2,2)))

typedef __attribute__((ext_vector_type(8))) short s8v;   // 8 bf16 (MFMA A/B)
typedef __attribute__((ext_vector_type(4))) float f4v;   // MFMA C/D

__device__ __forceinline__ unsigned short bf16rne(float v) {
    unsigned u = __float_as_uint(v);
    unsigned r = u + 0x7FFF + ((u >> 16) & 1);
    return (unsigned short)(r >> 16);
}
__device__ __forceinline__ float bf16tof(unsigned short h) {
    return __uint_as_float(((unsigned)h) << 16);
}
__device__ __forceinline__ float sigf(float x) { return 1.f / (1.f + __expf(-x)); }
__device__ __forceinline__ float tanhfast(float x) {
    float e = __expf(-2.f * x);
    return 2.f / (1.f + e) - 1.f;
}

#define PKFMA(acc, h, w) \
    asm("v_pk_fma_f32 %0, %1, %2, %0" : "+v"(acc) : "v"(h), "v"(w))

__device__ __forceinline__ float2 lo2(float4 v) { return make_float2(v.x, v.y); }
__device__ __forceinline__ float2 hi2(float4 v) { return make_float2(v.z, v.w); }

// 128-MAC dot as 64 v_pk_fma_f32 in TWO 16-load groups (was 8 groups of 4).
// 16 ds_read_b128 issue back-to-back and pipeline in the LDS unit -> one
// latency wait per group instead of eight (weights are AGPR-parked at
// VGPR_Count=88, so the old per-4-load pressure fencing is obsolete).
#define DOT128P(h4, wv, P0, P1, P2, P3)                                        \
    {                                                                          \
        _Pragma("unroll")                                                      \
        for (int g = 0; g < 2; ++g) {                                          \
            float4 cc[16];                                                     \
            _Pragma("unroll")                                                  \
            for (int q = 0; q < 16; ++q) cc[q] = (h4)[16*g + q];               \
            _Pragma("unroll")                                                  \
            for (int q = 0; q < 4; ++q) {                                      \
                PKFMA(P0, lo2(cc[4*q+0]), lo2(wv[16*g+4*q+0]));                \
                PKFMA(P1, hi2(cc[4*q+0]), hi2(wv[16*g+4*q+0]));                \
                PKFMA(P2, lo2(cc[4*q+1]), lo2(wv[16*g+4*q+1]));                \
                PKFMA(P3, hi2(cc[4*q+1]), hi2(wv[16*g+4*q+1]));                \
                PKFMA(P0, lo2(cc[4*q+2]), lo2(wv[16*g+4*q+2]));                \
                PKFMA(P1, hi2(cc[4*q+2]), hi2(wv[16*g+4*q+2]));                \
                PKFMA(P2, lo2(cc[4*q+3]), lo2(wv[16*g+4*q+3]));                \
                PKFMA(P3, hi2(cc[4*q+3]), hi2(wv[16*g+4*q+3]));                \
            }                                                                  \
            __builtin_amdgcn_sched_barrier(0);                                 \
        }                                                                      \
    }

// ---------------- K1: layer-0 recurrence — gate-colocated, 1 barrier/step ----------------
// Wave w owns h-rows [16w,16w+16); lane l computes gate row (l>>4)*128+16w+(l&15).
// All 4 gates of an h-row live in ONE wave -> i/f/g/o meet via shuffles (no gbuf,
// no barrier A). New h goes to the OTHER h_lds buffer -> 1 barrier/step total.
__global__ WGA
void lstm_layer0(const float* __restrict__ x,
                 const float* __restrict__ Wih, const float* __restrict__ Whh,
                 const float* __restrict__ bih, const float* __restrict__ bhh,
                 float* __restrict__ h1c,
                 float* __restrict__ hstate, float* __restrict__ cstate,
                 int t0, int len)
{
    __shared__ __align__(16) float h_lds[2][HD];
    __shared__ float x_lds[3 * TT];   // 12 KB
    const int j = threadIdx.x;
    const int b = blockIdx.x;
    const int w  = j >> 6;            // wave 0..7 -> h-rows [16w,16w+16)
    const int l  = j & 63;
    const int g  = l >> 4;            // gate type 0:i 1:f 2:g 3:o
    const int jj = l & 15;
    const int r  = g*HD + 16*w + jj;  // my gate row
    const int hh = 16*w + jj;         // my h-row (lanes l<16)

    float4 wv[HD/4];                  // W_hh row r (full 128)
    {
        const float4* wr = (const float4*)(Whh + (size_t)r * HD);
        #pragma unroll
        for (int q = 0; q < HD/4; ++q) wv[q] = wr[q];
    }
    const float wx0 = Wih[r*3+0], wx1 = Wih[r*3+1], wx2 = Wih[r*3+2];
    const float bias = bih[r] + bhh[r];
    // activation constants: act = s/(1+exp(m*acc)) + t  (bitwise == sigf/tanhfast)
    const float am = (g == 2) ? -2.f : -1.f;
    const float as = (g == 2) ?  2.f :  1.f;
    const float at = (g == 2) ? -1.f :  0.f;

    for (int idx = j; idx < 3*len; idx += 512)
        x_lds[idx] = x[((size_t)b*TT + t0)*3 + idx];

    float c = 0.f, hcur = 0.f;
    if (l < 16) {
        if (t0 != 0) { hcur = hstate[b*HD+hh]; c = cstate[b*HD+hh]; }
        h_lds[0][hh] = hcur;
    }
    __syncthreads();

    int cur = 0;
    for (int tc = 0; tc < len; ++tc) {
        float2 p0={0.f,0.f}, p1={0.f,0.f}, p2={0.f,0.f}, p3={0.f,0.f};
        const float4* h4 = (const float4*)h_lds[cur];   // wave-uniform broadcast
        DOT128P(h4, wv, p0, p1, p2, p3);
        float acc = bias + ((p0.x+p0.y)+(p1.x+p1.y)) + ((p2.x+p2.y)+(p3.x+p3.y));
        acc = fmaf(wx0, x_lds[3*tc+0], acc);
        acc = fmaf(wx1, x_lds[3*tc+1], acc);
        acc = fmaf(wx2, x_lds[3*tc+2], acc);
        float e = __expf(am * acc);
        float act = as / (1.f + e) + at;
        // gates of h-row jj: lanes jj, jj+16, jj+32, jj+48 of THIS wave
        float iv = __shfl(act, jj);
        float fv = __shfl(act, jj+16);
        float gv = __shfl(act, jj+32);
        float ov = __shfl(act, jj+48);
        if (l < 16) {
            c = fmaf(fv, c, iv*gv);
            hcur = ov * tanhfast(c);
            h_lds[cur^1][hh] = hcur;           // write OTHER buffer (no read race)
            h1c[((size_t)b*len + tc)*HD + hh] = hcur;
        }
        __syncthreads();                        // single barrier per step
        cur ^= 1;
    }
    if (l < 16) { hstate[b*HD+hh] = hcur; cstate[b*HD+hh] = c; }
}

// ---------------- K2: xg1 = h1 @ W_ih_l1^T + biases — MFMA GEMM (r18-proven, ~40us) ----------------
__global__ WGA
void xgate_gemm(const float* __restrict__ h1c,
                const float* __restrict__ Wih1,
                const float* __restrict__ bih1, const float* __restrict__ bhh1,
                float* __restrict__ xg1c, int len)
{
    __shared__ float bsum[NG];
    const int j = threadIdx.x;
    const int b = blockIdx.x;
    const int wv = j >> 6, lane = j & 63, lq = lane >> 4, lm = lane & 15;

    s8v Ah[4][4], Al[4][4];
    {
        #pragma unroll
        for (int t = 0; t < 4; ++t) {
            const int m = 64*wv + 16*t + lm;
            const float* wrow = Wih1 + (size_t)m * HD;
            #pragma unroll
            for (int kc = 0; kc < 4; ++kc) {
                const int k0 = 32*kc + 4*lq;
                float4 va = *(const float4*)(wrow + k0);
                float4 vb = *(const float4*)(wrow + k0 + 16);
                float vs[8] = {va.x,va.y,va.z,va.w,vb.x,vb.y,vb.z,vb.w};
                s8v ah, al;
                #pragma unroll
                for (int e = 0; e < 8; ++e) {
                    unsigned short hb = bf16rne(vs[e]);
                    float lo = vs[e] - bf16tof(hb);
                    ah[e] = (short)hb; al[e] = (short)bf16rne(lo);
                }
                Ah[t][kc] = ah; Al[t][kc] = al;
            }
        }
    }
    bsum[j] = bih1[j] + bhh1[j];
    __syncthreads();

    for (int ts = 0; ts < len; ts += 16) {
        const int trow = (ts + lm < len) ? (ts + lm) : (len - 1);
        const float* hrow = h1c + ((size_t)b*len + trow)*HD;
        s8v Bh[4], Bl[4];
        #pragma unroll
        for (int kc = 0; kc < 4; ++kc) {
            const int k0 = 32*kc + 4*lq;
            float4 va = *(const float4*)(hrow + k0);
            float4 vb = *(const float4*)(hrow + k0 + 16);
            float vs[8] = {va.x,va.y,va.z,va.w,vb.x,vb.y,vb.z,vb.w};
            s8v hhv, hlv;
            #pragma unroll
            for (int e = 0; e < 8; ++e) {
                unsigned short hb = bf16rne(vs[e]);
                float lo = vs[e] - bf16tof(hb);
                hhv[e] = (short)hb; hlv[e] = (short)bf16rne(lo);
            }
            Bh[kc] = hhv; Bl[kc] = hlv;
        }
        f4v zz = {0.f,0.f,0.f,0.f};
        f4v accA[4] = {zz,zz,zz,zz}, accB[4] = {zz,zz,zz,zz};
        #pragma unroll
        for (int kc = 0; kc < 4; ++kc) {
            #pragma unroll
            for (int t = 0; t < 4; ++t)
                accA[t] = __builtin_amdgcn_mfma_f32_16x16x32_bf16(Ah[t][kc], Bh[kc], accA[t], 0,0,0);
        }
        #pragma unroll
        for (int kc = 0; kc < 4; ++kc) {
            #pragma unroll
            for (int t = 0; t < 4; ++t)
                accB[t] = __builtin_amdgcn_mfma_f32_16x16x32_bf16(Al[t][kc], Bh[kc], accB[t], 0,0,0);
        }
        #pragma unroll
        for (int kc = 0; kc < 4; ++kc) {
            #pragma unroll
            for (int t = 0; t < 4; ++t)
                accB[t] = __builtin_amdgcn_mfma_f32_16x16x32_bf16(Ah[t][kc], Bl[kc], accB[t], 0,0,0);
        }
        if (ts + lm < len) {
            float* xrow = xg1c + ((size_t)b*len + ts + lm)*NG;
            #pragma unroll
            for (int t = 0; t < 4; ++t) {
                const int r0 = 64*wv + 16*t + 4*lq;
                float4 o;
                o.x = accA[t][0]+accB[t][0] + bsum[r0+0];
                o.y = accA[t][1]+accB[t][1] + bsum[r0+1];
                o.z = accA[t][2]+accB[t][2] + bsum[r0+2];
                o.w = accA[t][3]+accB[t][3] + bsum[r0+3];
                *(float4*)&xrow[r0] = o;
            }
        }
    }
}

// ---------------- K3: layer-1 recurrence — gate-colocated, 1 barrier/step ----------------
__global__ WGA
void lstm_layer1(const float* __restrict__ xg1c,
                 const float* __restrict__ Whh1,
                 float* __restrict__ h2c,
                 float* __restrict__ hstate, float* __restrict__ cstate,
                 int t0, int len)
{
    __shared__ __align__(16) float h_lds[2][HD];
    const int j = threadIdx.x;
    const int b = blockIdx.x;
    const int w  = j >> 6;
    const int l  = j & 63;
    const int g  = l >> 4;
    const int jj = l & 15;
    const int r  = g*HD + 16*w + jj;
    const int hh = 16*w + jj;

    float4 wv[HD/4];                  // W_hh_l1 row r
    {
        const float4* wr = (const float4*)(Whh1 + (size_t)r * HD);
        #pragma unroll
        for (int q = 0; q < HD/4; ++q) wv[q] = wr[q];
    }
    const float am = (g == 2) ? -2.f : -1.f;
    const float as = (g == 2) ?  2.f :  1.f;
    const float at = (g == 2) ? -1.f :  0.f;

    float c = 0.f, hcur = 0.f;
    if (l < 16) {
        if (t0 != 0) { hcur = hstate[b*HD+hh]; c = cstate[b*HD+hh]; }
        h_lds[0][hh] = hcur;
    }
    __syncthreads();

    float xg_cur = xg1c[((size_t)b*len + 0)*NG + r];   // my gate row's xg
    int cur = 0;
    for (int tc = 0; tc < len; ++tc) {
        float xg_nxt = 0.f;
        if (tc+1 < len) xg_nxt = xg1c[((size_t)b*len + tc+1)*NG + r]; // prefetch
        float2 p0={0.f,0.f}, p1={0.f,0.f}, p2={0.f,0.f}, p3={0.f,0.f};
        const float4* h4 = (const float4*)h_lds[cur];
        DOT128P(h4, wv, p0, p1, p2, p3);
        float acc = xg_cur + ((p0.x+p0.y)+(p1.x+p1.y)) + ((p2.x+p2.y)+(p3.x+p3.y));
        float e = __expf(am * acc);
        float act = as / (1.f + e) + at;
        float iv = __shfl(act, jj);
        float fv = __shfl(act, jj+16);
        float gv = __shfl(act, jj+32);
        float ov = __shfl(act, jj+48);
        if (l < 16) {
            c = fmaf(fv, c, iv*gv);
            hcur = ov * tanhfast(c);
            h_lds[cur^1][hh] = hcur;
            h2c[((size_t)b*len + tc)*HD + hh] = hcur;
        }
        __syncthreads();                        // single barrier per step
        cur ^= 1;
        xg_cur = xg_nxt;
    }
    if (l < 16) { hstate[b*HD+hh] = hcur; cstate[b*HD+hh] = c; }
}

// ---------------- K4: y = h2 @ fcw^T + fcb — wave-per-row, fp32 ----------------
__global__ __launch_bounds__(512, 1)
void fc_head(const float* __restrict__ h2c,
             const float* __restrict__ fcw, const float* __restrict__ fcb,
             float* __restrict__ y, int t0, int len)
{
    const int b = blockIdx.x;
    const int wid = threadIdx.x >> 6;
    const int lane = threadIdx.x & 63;
    const float f0a = fcw[0*HD+lane], f0b = fcw[0*HD+64+lane];
    const float f1a = fcw[1*HD+lane], f1b = fcw[1*HD+64+lane];
    const float f2a = fcw[2*HD+lane], f2b = fcw[2*HD+64+lane];
    const float fb = (lane < 3) ? fcb[lane] : 0.f;
    for (int tc = wid; tc < len; tc += 8) {
        const float* hp = h2c + ((size_t)b*len + tc)*HD;
        float ha = hp[lane], hb = hp[64+lane];
        float y0 = ha*f0a + hb*f0b;
        float y1 = ha*f1a + hb*f1b;
        float y2 = ha*f2a + hb*f2b;
        #pragma unroll
        for (int m = 1; m < 64; m <<= 1) {
            y0 += __shfl_xor(y0, m);
            y1 += __shfl_xor(y1, m);
            y2 += __shfl_xor(y2, m);
        }
        if (lane < 3) {
            float yv = (lane==0) ? y0 : (lane==1) ? y1 : y2;
            y[((size_t)b*TT + (t0+tc))*3 + lane] = yv + fb;
        }
    }
}

extern "C" void kernel_launch(void* const* d_in, const int* in_sizes, int n_in,
                              void* d_out, int out_size, void* d_ws, size_t ws_size,
                              hipStream_t stream)
{
    const float* x    = (const float*)d_in[0];
    const float* Wih0 = (const float*)d_in[1];
    const float* Whh0 = (const float*)d_in[2];
    const float* bih0 = (const float*)d_in[3];
    const float* bhh0 = (const float*)d_in[4];
    const float* Wih1 = (const float*)d_in[5];
    const float* Whh1 = (const float*)d_in[6];
    const float* bih1 = (const float*)d_in[7];
    const float* bhh1 = (const float*)d_in[8];
    const float* fcw  = (const float*)d_in[9];
    const float* fcb  = (const float*)d_in[10];
    float* y = (float*)d_out;

    // ws layout: h1 chunk + xg1 chunk + 4 state bufs (ws-derived -> deterministic)
    const size_t stateBytes = 4ull * NB * HD * sizeof(float);
    const size_t perT = (size_t)NB*HD*sizeof(float) + (size_t)NB*NG*sizeof(float);
    long tcl = (ws_size > stateBytes) ? (long)((ws_size - stateBytes) / perT) : 1;
    if (tcl > TT) tcl = TT;
    if (tcl < 1)  tcl = 1;
    const int Tc = (int)tcl;

    float* h1c  = (float*)d_ws;
    float* xg1c = h1c  + (size_t)NB * Tc * HD;
    float* hs1  = xg1c + (size_t)NB * Tc * NG;
    float* cs1  = hs1 + NB*HD;
    float* hs2  = cs1 + NB*HD;
    float* cs2  = hs2 + NB*HD;
    float* h2c  = h1c;   // h1c dead after K2 — reuse for h2

    for (int t0 = 0; t0 < TT; t0 += Tc) {
        const int len = (TT - t0 < Tc) ? (TT - t0) : Tc;
        lstm_layer0<<<dim3(NB), dim3(512), 0, stream>>>(
            x, Wih0, Whh0, bih0, bhh0, h1c, hs1, cs1, t0, len);
        xgate_gemm<<<dim3(NB), dim3(512), 0, stream>>>(
            h1c, Wih1, bih1, bhh1, xg1c, len);
        lstm_layer1<<<dim3(NB), dim3(512), 0, stream>>>(
            xg1c, Whh1, h2c, hs2, cs2, t0, len);
        fc_head<<<dim3(NB), dim3(512), 0, stream>>>(
            h2c, fcw, fcb, y, t0, len);
    }
}

// Round 25
// 1891.002 us; speedup vs baseline: 1.1498x; 1.1498x over previous
//
#include <hip/hip_runtime.h>

#define NB 256      // batch
#define TT 1000     // total timesteps
#define HD 128      // hidden
#define NG 512      // 4*H, PyTorch gate order i,f,g,o

// 8 waves/block at 1 block/CU = exactly 2 waves/EU (256-VGPR budget).
#define WGA __attribute__((amdgpu_flat_work_group_size(512,512), amdgpu_waves_per_eu(2,2)))

typedef __attribute__((ext_vector_type(8))) short s8v;   // 8 bf16 (MFMA A/B)
typedef __attribute__((ext_vector_type(4))) float f4v;   // MFMA C/D

__device__ __forceinline__ unsigned short bf16rne(float v) {
    unsigned u = __float_as_uint(v);
    unsigned r = u + 0x7FFF + ((u >> 16) & 1);
    return (unsigned short)(r >> 16);
}
__device__ __forceinline__ float bf16tof(unsigned short h) {
    return __uint_as_float(((unsigned)h) << 16);
}
__device__ __forceinline__ float sigf(float x) { return 1.f / (1.f + __expf(-x)); }
__device__ __forceinline__ float tanhfast(float x) {
    float e = __expf(-2.f * x);
    return 2.f / (1.f + e) - 1.f;
}

#define PKFMA(acc, h, w) \
    asm("v_pk_fma_f32 %0, %1, %2, %0" : "+v"(acc) : "v"(h), "v"(w))

__device__ __forceinline__ float2 lo2(float4 v) { return make_float2(v.x, v.y); }
__device__ __forceinline__ float2 hi2(float4 v) { return make_float2(v.z, v.w); }

// r20's 128-MAC dot as 64 v_pk_fma_f32 (issue-halved), wave-uniform broadcast reads.
// 4-load groups with sched_barrier(0): r24 showed 16-load groups regress (VGPR 88->112).
#define DOT128P(h4, wv, P0, P1, P2, P3)                                        \
    {                                                                          \
        _Pragma("unroll")                                                      \
        for (int g = 0; g < 8; ++g) {                                          \
            float4 c0=(h4)[4*g+0], c1=(h4)[4*g+1],                             \
                   c2=(h4)[4*g+2], c3=(h4)[4*g+3];                             \
            PKFMA(P0, lo2(c0), lo2(wv[4*g+0]));                                \
            PKFMA(P1, hi2(c0), hi2(wv[4*g+0]));                                \
            PKFMA(P2, lo2(c1), lo2(wv[4*g+1]));                                \
            PKFMA(P3, hi2(c1), hi2(wv[4*g+1]));                                \
            PKFMA(P0, lo2(c2), lo2(wv[4*g+2]));                                \
            PKFMA(P1, hi2(c2), hi2(wv[4*g+2]));                                \
            PKFMA(P2, lo2(c3), lo2(wv[4*g+3]));                                \
            PKFMA(P3, hi2(c3), hi2(wv[4*g+3]));                                \
            __builtin_amdgcn_sched_barrier(0);                                 \
        }                                                                      \
    }

// ---------------- K1: layer-0 recurrence — gate-colocated, 1 barrier/step ----------------
// Wave w owns h-rows [16w,16w+16); lane l computes gate row (l>>4)*128+16w+(l&15).
// All 4 gates of an h-row live in ONE wave -> i/f/g/o meet via shuffles (no gbuf,
// no barrier A). New h goes to the OTHER h_lds buffer -> 1 barrier/step total.
__global__ WGA
void lstm_layer0(const float* __restrict__ x,
                 const float* __restrict__ Wih, const float* __restrict__ Whh,
                 const float* __restrict__ bih, const float* __restrict__ bhh,
                 float* __restrict__ h1c,
                 float* __restrict__ hstate, float* __restrict__ cstate,
                 int t0, int len)
{
    __shared__ __align__(16) float h_lds[2][HD];
    __shared__ float x_lds[3 * TT];   // 12 KB
    const int j = threadIdx.x;
    const int b = blockIdx.x;
    const int w  = j >> 6;            // wave 0..7 -> h-rows [16w,16w+16)
    const int l  = j & 63;
    const int g  = l >> 4;            // gate type 0:i 1:f 2:g 3:o
    const int jj = l & 15;
    const int r  = g*HD + 16*w + jj;  // my gate row
    const int hh = 16*w + jj;         // my h-row (lanes l<16)

    float4 wv[HD/4];                  // W_hh row r (full 128)
    {
        const float4* wr = (const float4*)(Whh + (size_t)r * HD);
        #pragma unroll
        for (int q = 0; q < HD/4; ++q) wv[q] = wr[q];
    }
    const float wx0 = Wih[r*3+0], wx1 = Wih[r*3+1], wx2 = Wih[r*3+2];
    const float bias = bih[r] + bhh[r];
    // activation constants: act = s/(1+exp(m*acc)) + t  (bitwise == sigf/tanhfast)
    const float am = (g == 2) ? -2.f : -1.f;
    const float as = (g == 2) ?  2.f :  1.f;
    const float at = (g == 2) ? -1.f :  0.f;

    for (int idx = j; idx < 3*len; idx += 512)
        x_lds[idx] = x[((size_t)b*TT + t0)*3 + idx];

    float c = 0.f, hcur = 0.f;
    if (l < 16) {
        if (t0 != 0) { hcur = hstate[b*HD+hh]; c = cstate[b*HD+hh]; }
        h_lds[0][hh] = hcur;
    }
    __syncthreads();

    int cur = 0;
    for (int tc = 0; tc < len; ++tc) {
        float2 p0={0.f,0.f}, p1={0.f,0.f}, p2={0.f,0.f}, p3={0.f,0.f};
        const float4* h4 = (const float4*)h_lds[cur];   // wave-uniform broadcast
        DOT128P(h4, wv, p0, p1, p2, p3);
        float acc = bias + ((p0.x+p0.y)+(p1.x+p1.y)) + ((p2.x+p2.y)+(p3.x+p3.y));
        acc = fmaf(wx0, x_lds[3*tc+0], acc);
        acc = fmaf(wx1, x_lds[3*tc+1], acc);
        acc = fmaf(wx2, x_lds[3*tc+2], acc);
        float e = __expf(am * acc);
        float act = as / (1.f + e) + at;
        // gates of h-row jj: lanes jj, jj+16, jj+32, jj+48 of THIS wave
        float iv = __shfl(act, jj);
        float fv = __shfl(act, jj+16);
        float gv = __shfl(act, jj+32);
        float ov = __shfl(act, jj+48);
        if (l < 16) {
            c = fmaf(fv, c, iv*gv);
            hcur = ov * tanhfast(c);
            h_lds[cur^1][hh] = hcur;           // write OTHER buffer (no read race)
            h1c[((size_t)b*len + tc)*HD + hh] = hcur;
        }
        __syncthreads();                        // single barrier per step
        cur ^= 1;
    }
    if (l < 16) { hstate[b*HD+hh] = hcur; cstate[b*HD+hh] = c; }
}

// ---------------- K2: xg1 = h1 @ W_ih_l1^T + biases — MFMA GEMM (r18-proven, ~40us) ----------------
__global__ WGA
void xgate_gemm(const float* __restrict__ h1c,
                const float* __restrict__ Wih1,
                const float* __restrict__ bih1, const float* __restrict__ bhh1,
                float* __restrict__ xg1c, int len)
{
    __shared__ float bsum[NG];
    const int j = threadIdx.x;
    const int b = blockIdx.x;
    const int wv = j >> 6, lane = j & 63, lq = lane >> 4, lm = lane & 15;

    s8v Ah[4][4], Al[4][4];
    {
        #pragma unroll
        for (int t = 0; t < 4; ++t) {
            const int m = 64*wv + 16*t + lm;
            const float* wrow = Wih1 + (size_t)m * HD;
            #pragma unroll
            for (int kc = 0; kc < 4; ++kc) {
                const int k0 = 32*kc + 4*lq;
                float4 va = *(const float4*)(wrow + k0);
                float4 vb = *(const float4*)(wrow + k0 + 16);
                float vs[8] = {va.x,va.y,va.z,va.w,vb.x,vb.y,vb.z,vb.w};
                s8v ah, al;
                #pragma unroll
                for (int e = 0; e < 8; ++e) {
                    unsigned short hb = bf16rne(vs[e]);
                    float lo = vs[e] - bf16tof(hb);
                    ah[e] = (short)hb; al[e] = (short)bf16rne(lo);
                }
                Ah[t][kc] = ah; Al[t][kc] = al;
            }
        }
    }
    bsum[j] = bih1[j] + bhh1[j];
    __syncthreads();

    for (int ts = 0; ts < len; ts += 16) {
        const int trow = (ts + lm < len) ? (ts + lm) : (len - 1);
        const float* hrow = h1c + ((size_t)b*len + trow)*HD;
        s8v Bh[4], Bl[4];
        #pragma unroll
        for (int kc = 0; kc < 4; ++kc) {
            const int k0 = 32*kc + 4*lq;
            float4 va = *(const float4*)(hrow + k0);
            float4 vb = *(const float4*)(hrow + k0 + 16);
            float vs[8] = {va.x,va.y,va.z,va.w,vb.x,vb.y,vb.z,vb.w};
            s8v hhv, hlv;
            #pragma unroll
            for (int e = 0; e < 8; ++e) {
                unsigned short hb = bf16rne(vs[e]);
                float lo = vs[e] - bf16tof(hb);
                hhv[e] = (short)hb; hlv[e] = (short)bf16rne(lo);
            }
            Bh[kc] = hhv; Bl[kc] = hlv;
        }
        f4v zz = {0.f,0.f,0.f,0.f};
        f4v accA[4] = {zz,zz,zz,zz}, accB[4] = {zz,zz,zz,zz};
        #pragma unroll
        for (int kc = 0; kc < 4; ++kc) {
            #pragma unroll
            for (int t = 0; t < 4; ++t)
                accA[t] = __builtin_amdgcn_mfma_f32_16x16x32_bf16(Ah[t][kc], Bh[kc], accA[t], 0,0,0);
        }
        #pragma unroll
        for (int kc = 0; kc < 4; ++kc) {
            #pragma unroll
            for (int t = 0; t < 4; ++t)
                accB[t] = __builtin_amdgcn_mfma_f32_16x16x32_bf16(Al[t][kc], Bh[kc], accB[t], 0,0,0);
        }
        #pragma unroll
        for (int kc = 0; kc < 4; ++kc) {
            #pragma unroll
            for (int t = 0; t < 4; ++t)
                accB[t] = __builtin_amdgcn_mfma_f32_16x16x32_bf16(Ah[t][kc], Bl[kc], accB[t], 0,0,0);
        }
        if (ts + lm < len) {
            float* xrow = xg1c + ((size_t)b*len + ts + lm)*NG;
            #pragma unroll
            for (int t = 0; t < 4; ++t) {
                const int r0 = 64*wv + 16*t + 4*lq;
                float4 o;
                o.x = accA[t][0]+accB[t][0] + bsum[r0+0];
                o.y = accA[t][1]+accB[t][1] + bsum[r0+1];
                o.z = accA[t][2]+accB[t][2] + bsum[r0+2];
                o.w = accA[t][3]+accB[t][3] + bsum[r0+3];
                *(float4*)&xrow[r0] = o;
            }
        }
    }
}

// ---------------- K3: layer-1 recurrence — gate-colocated, 1 barrier/step ----------------
__global__ WGA
void lstm_layer1(const float* __restrict__ xg1c,
                 const float* __restrict__ Whh1,
                 float* __restrict__ h2c,
                 float* __restrict__ hstate, float* __restrict__ cstate,
                 int t0, int len)
{
    __shared__ __align__(16) float h_lds[2][HD];
    const int j = threadIdx.x;
    const int b = blockIdx.x;
    const int w  = j >> 6;
    const int l  = j & 63;
    const int g  = l >> 4;
    const int jj = l & 15;
    const int r  = g*HD + 16*w + jj;
    const int hh = 16*w + jj;

    float4 wv[HD/4];                  // W_hh_l1 row r
    {
        const float4* wr = (const float4*)(Whh1 + (size_t)r * HD);
        #pragma unroll
        for (int q = 0; q < HD/4; ++q) wv[q] = wr[q];
    }
    const float am = (g == 2) ? -2.f : -1.f;
    const float as = (g == 2) ?  2.f :  1.f;
    const float at = (g == 2) ? -1.f :  0.f;

    float c = 0.f, hcur = 0.f;
    if (l < 16) {
        if (t0 != 0) { hcur = hstate[b*HD+hh]; c = cstate[b*HD+hh]; }
        h_lds[0][hh] = hcur;
    }
    __syncthreads();

    float xg_cur = xg1c[((size_t)b*len + 0)*NG + r];   // my gate row's xg
    int cur = 0;
    for (int tc = 0; tc < len; ++tc) {
        float xg_nxt = 0.f;
        if (tc+1 < len) xg_nxt = xg1c[((size_t)b*len + tc+1)*NG + r]; // prefetch
        float2 p0={0.f,0.f}, p1={0.f,0.f}, p2={0.f,0.f}, p3={0.f,0.f};
        const float4* h4 = (const float4*)h_lds[cur];
        DOT128P(h4, wv, p0, p1, p2, p3);
        float acc = xg_cur + ((p0.x+p0.y)+(p1.x+p1.y)) + ((p2.x+p2.y)+(p3.x+p3.y));
        float e = __expf(am * acc);
        float act = as / (1.f + e) + at;
        float iv = __shfl(act, jj);
        float fv = __shfl(act, jj+16);
        float gv = __shfl(act, jj+32);
        float ov = __shfl(act, jj+48);
        if (l < 16) {
            c = fmaf(fv, c, iv*gv);
            hcur = ov * tanhfast(c);
            h_lds[cur^1][hh] = hcur;
            h2c[((size_t)b*len + tc)*HD + hh] = hcur;
        }
        __syncthreads();                        // single barrier per step
        cur ^= 1;
        xg_cur = xg_nxt;
    }
    if (l < 16) { hstate[b*HD+hh] = hcur; cstate[b*HD+hh] = c; }
}

// ---------------- K4: y = h2 @ fcw^T + fcb — wave-per-row, fp32 ----------------
__global__ __launch_bounds__(512, 1)
void fc_head(const float* __restrict__ h2c,
             const float* __restrict__ fcw, const float* __restrict__ fcb,
             float* __restrict__ y, int t0, int len)
{
    const int b = blockIdx.x;
    const int wid = threadIdx.x >> 6;
    const int lane = threadIdx.x & 63;
    const float f0a = fcw[0*HD+lane], f0b = fcw[0*HD+64+lane];
    const float f1a = fcw[1*HD+lane], f1b = fcw[1*HD+64+lane];
    const float f2a = fcw[2*HD+lane], f2b = fcw[2*HD+64+lane];
    const float fb = (lane < 3) ? fcb[lane] : 0.f;
    for (int tc = wid; tc < len; tc += 8) {
        const float* hp = h2c + ((size_t)b*len + tc)*HD;
        float ha = hp[lane], hb = hp[64+lane];
        float y0 = ha*f0a + hb*f0b;
        float y1 = ha*f1a + hb*f1b;
        float y2 = ha*f2a + hb*f2b;
        #pragma unroll
        for (int m = 1; m < 64; m <<= 1) {
            y0 += __shfl_xor(y0, m);
            y1 += __shfl_xor(y1, m);
            y2 += __shfl_xor(y2, m);
        }
        if (lane < 3) {
            float yv = (lane==0) ? y0 : (lane==1) ? y1 : y2;
            y[((size_t)b*TT + (t0+tc))*3 + lane] = yv + fb;
        }
    }
}

extern "C" void kernel_launch(void* const* d_in, const int* in_sizes, int n_in,
                              void* d_out, int out_size, void* d_ws, size_t ws_size,
                              hipStream_t stream)
{
    const float* x    = (const float*)d_in[0];
    const float* Wih0 = (const float*)d_in[1];
    const float* Whh0 = (const float*)d_in[2];
    const float* bih0 = (const float*)d_in[3];
    const float* bhh0 = (const float*)d_in[4];
    const float* Wih1 = (const float*)d_in[5];
    const float* Whh1 = (const float*)d_in[6];
    const float* bih1 = (const float*)d_in[7];
    const float* bhh1 = (const float*)d_in[8];
    const float* fcw  = (const float*)d_in[9];
    const float* fcb  = (const float*)d_in[10];
    float* y = (float*)d_out;

    // ws layout: h1 chunk + xg1 chunk + 4 state bufs (ws-derived -> deterministic)
    const size_t stateBytes = 4ull * NB * HD * sizeof(float);
    const size_t perT = (size_t)NB*HD*sizeof(float) + (size_t)NB*NG*sizeof(float);
    long tcl = (ws_size > stateBytes) ? (long)((ws_size - stateBytes) / perT) : 1;
    if (tcl > TT) tcl = TT;
    if (tcl < 1)  tcl = 1;
    const int Tc = (int)tcl;

    float* h1c  = (float*)d_ws;
    float* xg1c = h1c  + (size_t)NB * Tc * HD;
    float* hs1  = xg1c + (size_t)NB * Tc * NG;
    float* cs1  = hs1 + NB*HD;
    float* hs2  = cs1 + NB*HD;
    float* cs2  = hs2 + NB*HD;
    float* h2c  = h1c;   // h1c dead after K2 — reuse for h2

    for (int t0 = 0; t0 < TT; t0 += Tc) {
        const int len = (TT - t0 < Tc) ? (TT - t0) : Tc;
        lstm_layer0<<<dim3(NB), dim3(512), 0, stream>>>(
            x, Wih0, Whh0, bih0, bhh0, h1c, hs1, cs1, t0, len);
        xgate_gemm<<<dim3(NB), dim3(512), 0, stream>>>(
            h1c, Wih1, bih1, bhh1, xg1c, len);
        lstm_layer1<<<dim3(NB), dim3(512), 0, stream>>>(
            xg1c, Whh1, h2c, hs2, cs2, t0, len);
        fc_head<<<dim3(NB), dim3(512), 0, stream>>>(
            h2c, fcw, fcb, y, t0, len);
    }
}